// Round 1
// baseline (1093.023 us; speedup 1.0000x reference)
//
#include <hip/hip_runtime.h>
#include <hip/hip_bf16.h>

#define KIMG 5
#define CCH 256
#define NPIX 4096      // 64*64
#define NH 8
#define DH 32
#define SPAT 256       // S = 16*16 patches
#define LL 16          // Hp*Wp
#define M2 2560        // K*2*S

// ---------------- weight transpose ----------------
__global__ void transpose_w(const float* __restrict__ wq, const float* __restrict__ wsm,
                            float* __restrict__ wqT, float* __restrict__ wsT) {
    int gidx = blockIdx.x * 256 + threadIdx.x;   // 0..65535
    int ci = gidx >> 8, co = gidx & 255;
    const float* src = blockIdx.y ? wsm : wq;
    float* dst = blockIdx.y ? wsT : wqT;
    dst[gidx] = src[co * 256 + ci];
    (void)ci;
}

// ---------------- feature GEMM: F[img][p][co] = sum_ci x[img][ci][p]*w[co][ci] + b[co] ----------------
__global__ __launch_bounds__(256) void feat_gemm(const float* __restrict__ x,
                                                 const float* __restrict__ wqT, const float* __restrict__ wsT,
                                                 const float* __restrict__ bq, const float* __restrict__ bs,
                                                 float* __restrict__ Fout) {
    int img = blockIdx.z;
    int p0 = blockIdx.x * 64, co0 = blockIdx.y * 64;
    const float* wT = (img == 0) ? wqT : wsT;
    const float* bias = (img == 0) ? bq : bs;
    __shared__ float As[32][64];
    __shared__ float Bs[32][64];
    int tid = threadIdx.x;
    int tx = tid & 15, ty = tid >> 4;
    float acc[4][4] = {};
    const float* xim = x + (size_t)img * CCH * NPIX;
    for (int k0 = 0; k0 < 256; k0 += 32) {
#pragma unroll
        for (int r = 0; r < 8; r++) {
            int idx = r * 256 + tid;
            int kk = idx >> 6, px = idx & 63;
            As[kk][px] = xim[(size_t)(k0 + kk) * NPIX + p0 + px];
        }
#pragma unroll
        for (int r = 0; r < 8; r++) {
            int idx = r * 256 + tid;
            int kk = idx >> 6, co = idx & 63;
            Bs[kk][co] = wT[(size_t)(k0 + kk) * 256 + co0 + co];
        }
        __syncthreads();
#pragma unroll
        for (int kk = 0; kk < 32; kk++) {
            float4 av = *(const float4*)(&As[kk][ty * 4]);
            float4 bv = *(const float4*)(&Bs[kk][tx * 4]);
            float a4[4] = {av.x, av.y, av.z, av.w};
            float b4[4] = {bv.x, bv.y, bv.z, bv.w};
#pragma unroll
            for (int i = 0; i < 4; i++)
#pragma unroll
                for (int jj = 0; jj < 4; jj++)
                    acc[i][jj] = fmaf(a4[i], b4[jj], acc[i][jj]);
        }
        __syncthreads();
    }
#pragma unroll
    for (int i = 0; i < 4; i++) {
        int p = p0 + ty * 4 + i;
        float4 v;
        v.x = acc[i][0] + bias[co0 + tx * 4 + 0];
        v.y = acc[i][1] + bias[co0 + tx * 4 + 1];
        v.z = acc[i][2] + bias[co0 + tx * 4 + 2];
        v.w = acc[i][3] + bias[co0 + tx * 4 + 3];
        *(float4*)(&Fout[((size_t)img * NPIX + p) * CCH + co0 + tx * 4]) = v;
    }
}

// ---------------- centroids ----------------
// grid (256, 5): block = (s, k). 256 threads = 8 heads x 32 d.
__global__ __launch_bounds__(256) void centroid_kernel(const float* __restrict__ F, const float* __restrict__ dox,
                                                       float* __restrict__ Cs, float* __restrict__ mflag) {
    int s = blockIdx.x, k = blockIdx.y;
    int p1 = s >> 4, p2 = s & 15;
    __shared__ float wfg[16];
    __shared__ int pix[16];
    int tid = threadIdx.x;
    if (tid < 16) {
        int hp = tid >> 2, wp = tid & 3;
        int y = p1 * 4 + hp, x = p2 * 4 + wp;
        pix[tid] = y * 64 + x;
        // delta = nearest-resize of (256,256) onehot to (64,64): [4y][4x]
        wfg[tid] = dox[(size_t)k * 65536 + (4 * y) * 256 + 4 * x];
    }
    __syncthreads();
    float fsum = 0.0f;
#pragma unroll
    for (int l = 0; l < 16; l++) fsum += wfg[l];
    float bsum = 16.0f - fsum;
    int h = tid >> 5, dd = tid & 31;
    const float* Fk = F + (size_t)(k + 1) * NPIX * CCH;
    float afg = 0.0f, abg = 0.0f;
#pragma unroll
    for (int l = 0; l < 16; l++) {
        float v = Fk[(size_t)pix[l] * CCH + h * DH + dd];
        float wl = wfg[l];
        afg = fmaf(wl, v, afg);
        abg += v - wl * v;
    }
    float fgs = fmaxf(fsum, 1e-6f), bgs = fmaxf(bsum, 1e-6f);
    int mf = k * 512 + s, mb = mf + 256;
    Cs[((size_t)h * M2 + mf) * DH + dd] = afg / fgs;
    Cs[((size_t)h * M2 + mb) * DH + dd] = abg / bgs;
    if (tid == 0) {
        mflag[mf] = (fsum < 1.0f) ? 1.0f : 0.0f;
        mflag[mb] = (bsum < 1.0f) ? 1.0f : 0.0f;
    }
}

// ---------------- attention + online softmax + fg-prob sum ----------------
__device__ __forceinline__ void osm_update(float d, bool isfg, float& m, float& s, float& f) {
    if (d > m) {
        float sc = __expf(m - d);
        s *= sc; f *= sc; m = d;
        s += 1.0f; if (isfg) f += 1.0f;
    } else {
        float e = __expf(d - m);
        s += e; if (isfg) f += e;
    }
}

// grid (64, 8): (pixel-tile of 64, head). 256 threads: pl2 = tid&31 -> pixels pl2, pl2+32; j = tid>>5 -> m-stripe.
__global__ __launch_bounds__(256) void attn_kernel(const float* __restrict__ F, const float* __restrict__ Cs,
                                                   const float* __restrict__ mflag, float* __restrict__ aout) {
    int head = blockIdx.y;
    int p0 = blockIdx.x * 64;
    int tid = threadIdx.x;
    __shared__ float Qs[64][32];
    __shared__ float Csh[64][32];
    __shared__ float mfl[64];
    __shared__ float Pm[8][64], Ps[8][64], Pf[8][64];
#pragma unroll
    for (int r = 0; r < 8; r++) {
        int idx = r * 256 + tid;
        int pl = idx >> 5, dd = idx & 31;
        Qs[pl][dd] = F[(size_t)(p0 + pl) * CCH + head * DH + dd];
    }
    __syncthreads();
    int pl2 = tid & 31, j = tid >> 5;
    float qa[32], qb[32];
#pragma unroll
    for (int i = 0; i < 32; i++) { qa[i] = Qs[pl2][i]; qb[i] = Qs[pl2 + 32][i]; }
    float mr0 = -1e30f, mr1 = -1e30f, sr0 = 0.0f, sr1 = 0.0f, fr0 = 0.0f, fr1 = 0.0f;
    for (int c0 = 0; c0 < M2; c0 += 64) {
        __syncthreads();
#pragma unroll
        for (int r = 0; r < 8; r++) {
            int idx = r * 256 + tid;
            int ml = idx >> 5, dd = idx & 31;
            Csh[ml][dd] = Cs[((size_t)head * M2 + c0 + ml) * DH + dd];
        }
        if (tid < 64) mfl[tid] = mflag[c0 + tid];
        __syncthreads();
#pragma unroll
        for (int mi = 0; mi < 8; mi++) {
            int ml = j * 8 + mi;
            if (mfl[ml] != 0.0f) continue;   // masked -> -inf -> contributes 0
            int m = c0 + ml;
            bool isfg = (m & 511) < 256;
            float d0 = 0.0f, d1 = 0.0f;
#pragma unroll
            for (int i = 0; i < 32; i++) {
                float cv = Csh[ml][i];
                d0 = fmaf(qa[i], cv, d0);
                d1 = fmaf(qb[i], cv, d1);
            }
            osm_update(d0, isfg, mr0, sr0, fr0);
            osm_update(d1, isfg, mr1, sr1, fr1);
        }
    }
    Pm[j][pl2] = mr0; Ps[j][pl2] = sr0; Pf[j][pl2] = fr0;
    Pm[j][pl2 + 32] = mr1; Ps[j][pl2 + 32] = sr1; Pf[j][pl2 + 32] = fr1;
    __syncthreads();
    if (tid < 64) {
        float mx = -1e30f;
#pragma unroll
        for (int jj = 0; jj < 8; jj++) mx = fmaxf(mx, Pm[jj][tid]);
        float st = 0.0f, ft = 0.0f;
#pragma unroll
        for (int jj = 0; jj < 8; jj++) {
            float sc = __expf(Pm[jj][tid] - mx);
            st = fmaf(Ps[jj][tid], sc, st);
            ft = fmaf(Pf[jj][tid], sc, ft);
        }
        aout[(size_t)head * NPIX + p0 + tid] = ft / st;
    }
}

// ---------------- head mean ----------------
__global__ void mean_heads(const float* __restrict__ attnout, float* __restrict__ cm) {
    int idx = blockIdx.x * 256 + threadIdx.x;   // 16384
    int sc = idx >> 12, p = idx & 4095;
    const float* a = attnout + (size_t)sc * NH * NPIX + p;
    float s = 0.0f;
#pragma unroll
    for (int h = 0; h < NH; h++) s += a[(size_t)h * NPIX];
    cm[idx] = 0.125f * s;
}

// ---------------- convs ----------------
__global__ __launch_bounds__(256) void conv5x5(const float* __restrict__ in, const float* __restrict__ wgt,
                                               const float* __restrict__ bias, int Cin, float* __restrict__ out) {
    int oc = blockIdx.x;
    int p = blockIdx.y * 256 + threadIdx.x;
    int y = p >> 6, x = p & 63;
    float acc = bias[oc];
    for (int ic = 0; ic < Cin; ic++) {
        const float* ip = in + (size_t)ic * NPIX;
        const float* wp = wgt + ((size_t)oc * Cin + ic) * 25;
#pragma unroll
        for (int ky = 0; ky < 5; ky++) {
            int iy = y + ky - 2;
            if ((unsigned)iy >= 64u) continue;
#pragma unroll
            for (int kx = 0; kx < 5; kx++) {
                int ix = x + kx - 2;
                if ((unsigned)ix >= 64u) continue;
                acc = fmaf(ip[iy * 64 + ix], wp[ky * 5 + kx], acc);
            }
        }
    }
    out[(size_t)oc * NPIX + p] = acc;
}

__global__ __launch_bounds__(256) void conv3x3(const float* __restrict__ in, const float* __restrict__ wgt,
                                               const float* __restrict__ bias, int Cin, float* __restrict__ out) {
    int oc = blockIdx.x;
    int p = blockIdx.y * 256 + threadIdx.x;
    int y = p >> 6, x = p & 63;
    float acc = bias[oc];
    for (int ic = 0; ic < Cin; ic++) {
        const float* ip = in + (size_t)ic * NPIX;
        const float* wp = wgt + ((size_t)oc * Cin + ic) * 9;
#pragma unroll
        for (int ky = 0; ky < 3; ky++) {
            int iy = y + ky - 1;
            if ((unsigned)iy >= 64u) continue;
#pragma unroll
            for (int kx = 0; kx < 3; kx++) {
                int ix = x + kx - 1;
                if ((unsigned)ix >= 64u) continue;
                acc = fmaf(ip[iy * 64 + ix], wp[ky * 3 + kx], acc);
            }
        }
    }
    out[(size_t)oc * NPIX + p] = acc;
}

// ---------------- group norm ----------------
__global__ __launch_bounds__(256) void gn_stats(const float* __restrict__ in, int Cg, float* __restrict__ gnp) {
    int g = blockIdx.x;
    int n = Cg * NPIX;
    const float* base = in + (size_t)g * n;
    float s = 0.0f, s2 = 0.0f;
    for (int i = threadIdx.x; i < n; i += 256) {
        float v = base[i];
        s += v;
        s2 = fmaf(v, v, s2);
    }
#pragma unroll
    for (int off = 32; off; off >>= 1) {
        s += __shfl_down(s, off);
        s2 += __shfl_down(s2, off);
    }
    __shared__ float rs[4], rs2[4];
    int w = threadIdx.x >> 6;
    if ((threadIdx.x & 63) == 0) { rs[w] = s; rs2[w] = s2; }
    __syncthreads();
    if (threadIdx.x == 0) {
        float S = rs[0] + rs[1] + rs[2] + rs[3];
        float S2 = rs2[0] + rs2[1] + rs2[2] + rs2[3];
        float mu = S / n;
        float var = S2 / n - mu * mu;
        gnp[g * 2] = mu;
        gnp[g * 2 + 1] = rsqrtf(var + 1e-5f);
    }
}

__global__ void gn_apply_relu(const float* __restrict__ in, const float* __restrict__ gnp,
                              const float* __restrict__ gamma, const float* __restrict__ beta,
                              int Cg, float* __restrict__ out) {
    int idx = blockIdx.x * 256 + threadIdx.x;
    int c = idx >> 12;
    int g = c / Cg;
    float mu = gnp[g * 2], rs = gnp[g * 2 + 1];
    float v = (in[idx] - mu) * rs * gamma[c] + beta[c];
    out[idx] = v > 0.0f ? v : 0.0f;
}

// ---------------- launch ----------------
extern "C" void kernel_launch(void* const* d_in, const int* in_sizes, int n_in,
                              void* d_out, int out_size, void* d_ws, size_t ws_size,
                              hipStream_t stream) {
    const float* x[4] = {(const float*)d_in[0], (const float*)d_in[1], (const float*)d_in[2], (const float*)d_in[3]};
    const float* dox = (const float*)d_in[4];
    const float* wq  = (const float*)d_in[5];
    const float* bq  = (const float*)d_in[6];
    const float* wsm = (const float*)d_in[7];
    const float* bs  = (const float*)d_in[8];
    const float* cw1 = (const float*)d_in[9];
    const float* cb1 = (const float*)d_in[10];
    const float* g1  = (const float*)d_in[11];
    const float* be1 = (const float*)d_in[12];
    const float* cw2 = (const float*)d_in[13];
    const float* cb2 = (const float*)d_in[14];
    const float* g2  = (const float*)d_in[15];
    const float* be2 = (const float*)d_in[16];
    const float* cw3 = (const float*)d_in[17];
    const float* cb3 = (const float*)d_in[18];
    const float* g3  = (const float*)d_in[19];
    const float* be3 = (const float*)d_in[20];

    float* wsf = (float*)d_ws;
    float* wqT = wsf;                           // 65536
    float* wsT = wqT + 65536;                   // 65536
    float* Fbuf = wsT + 65536;                  // 6*4096*256 = 6291456
    float* Cs = Fbuf + (size_t)6 * NPIX * CCH;  // 8*2560*32 = 655360
    float* mflag = Cs + (size_t)NH * M2 * DH;   // 2560
    float* attnout = mflag + M2;                // 4*8*4096 = 131072
    float* cm = attnout + (size_t)4 * NH * NPIX;// 16384
    float* h1 = cm + 4 * NPIX;                  // 65536
    float* h2 = h1 + 16 * NPIX;                 // 262144
    float* h3 = h2 + 64 * NPIX;                 // 524288
    float* gnp = h3 + 128 * NPIX;               // 8

    transpose_w<<<dim3(256, 2), 256, 0, stream>>>(wq, wsm, wqT, wsT);

    for (int sc = 0; sc < 4; sc++) {
        feat_gemm<<<dim3(64, 4, 6), 256, 0, stream>>>(x[sc], wqT, wsT, bq, bs, Fbuf);
        centroid_kernel<<<dim3(256, 5), 256, 0, stream>>>(Fbuf, dox, Cs, mflag);
        attn_kernel<<<dim3(64, 8), 256, 0, stream>>>(Fbuf, Cs, mflag, attnout + (size_t)sc * NH * NPIX);
    }

    mean_heads<<<64, 256, 0, stream>>>(attnout, cm);

    conv5x5<<<dim3(16, 16), 256, 0, stream>>>(cm, cw1, cb1, 4, h1);
    gn_stats<<<4, 256, 0, stream>>>(h1, 4, gnp);
    gn_apply_relu<<<(16 * NPIX) / 256, 256, 0, stream>>>(h1, gnp, g1, be1, 4, h1);

    conv5x5<<<dim3(64, 16), 256, 0, stream>>>(h1, cw2, cb2, 16, h2);
    gn_stats<<<4, 256, 0, stream>>>(h2, 16, gnp);
    gn_apply_relu<<<(64 * NPIX) / 256, 256, 0, stream>>>(h2, gnp, g2, be2, 16, h2);

    conv3x3<<<dim3(128, 16), 256, 0, stream>>>(h2, cw3, cb3, 64, h3);
    gn_stats<<<4, 256, 0, stream>>>(h3, 32, gnp);
    gn_apply_relu<<<(128 * NPIX) / 256, 256, 0, stream>>>(h3, gnp, g3, be3, 32, (float*)d_out);
}

// Round 2
// 574.752 us; speedup vs baseline: 1.9017x; 1.9017x over previous
//
#include <hip/hip_runtime.h>
#include <hip/hip_bf16.h>
#include <stdint.h>

#define CCH 256
#define NPIX 4096      // 64*64
#define NH 8
#define M2 2560        // K*2*S
#define LOG2E 1.44269504088896f

typedef __attribute__((ext_vector_type(8))) short short8;
typedef __attribute__((ext_vector_type(4))) float f32x4;

__device__ __forceinline__ uint16_t f2bfu(float f) {
    uint32_t u = __builtin_bit_cast(uint32_t, f);
    return (uint16_t)((u + 0x7FFFu + ((u >> 16) & 1u)) >> 16);   // RNE
}
__device__ __forceinline__ uint32_t pack_bf2(float a, float b) {
    return (uint32_t)f2bfu(a) | ((uint32_t)f2bfu(b) << 16);
}
__device__ __forceinline__ short8 mk8(uint32_t a, uint32_t b, uint32_t c, uint32_t d) {
    union { uint32_t u[4]; short8 s; } t;
    t.u[0] = a; t.u[1] = b; t.u[2] = c; t.u[3] = d;
    return t.s;
}

// ---------------- feature GEMM (bf16 MFMA): F[img][px][co] = X[img][:, px] . W[co][:] + b ----------------
// block: 128 px x 64 co, 4 waves (each 64px x 32co = 4x2 tiles of 16x16), K-step 32.
__global__ __launch_bounds__(256) void feat_gemm_mfma(
        const float* __restrict__ x, const float* __restrict__ wq, const float* __restrict__ wsm,
        const float* __restrict__ bq, const float* __restrict__ bs,
        float* __restrict__ F5, uint16_t* __restrict__ Qbf) {
    int img = blockIdx.z;
    int p0 = blockIdx.x * 128, co0 = blockIdx.y * 64;
    const float* w    = img ? wsm : wq;
    const float* bias = img ? bs  : bq;
    const float* xim  = x + (size_t)img * CCH * NPIX;
    __shared__ uint32_t Al[128][18];   // [px][k-pair], pad 18 u32 rows (72B)
    int tid = threadIdx.x;
    int lane = tid & 63, wid = tid >> 6;
    int lp = lane & 15, g = lane >> 4;
    int wm = wid & 1, wn = wid >> 1;

    f32x4 acc[4][2] = {};
    int spx = tid & 127, kp0 = tid >> 7;

#pragma unroll
    for (int ks = 0; ks < 8; ks++) {
        int k0 = ks * 32;
        __syncthreads();
        // stage A tile (transpose + f32->bf16 pack): 128px x 32k
#pragma unroll
        for (int it = 0; it < 8; it++) {
            int kp = kp0 + it * 2;
            float v0 = xim[(size_t)(k0 + 2 * kp) * NPIX + p0 + spx];
            float v1 = xim[(size_t)(k0 + 2 * kp + 1) * NPIX + p0 + spx];
            Al[spx][kp] = pack_bf2(v0, v1);
        }
        __syncthreads();
        // B fragments straight from global w (row-major [co][ci] == B-frag layout)
        short8 bfr[2];
#pragma unroll
        for (int tn = 0; tn < 2; tn++) {
            int co = co0 + wn * 32 + tn * 16 + lp;
            const float* wr = w + (size_t)co * 256 + k0 + g * 8;
            float4 f0 = *(const float4*)wr;
            float4 f1 = *(const float4*)(wr + 4);
            bfr[tn] = mk8(pack_bf2(f0.x, f0.y), pack_bf2(f0.z, f0.w),
                          pack_bf2(f1.x, f1.y), pack_bf2(f1.z, f1.w));
        }
#pragma unroll
        for (int tm = 0; tm < 4; tm++) {
            const uint32_t* rp = &Al[wm * 64 + tm * 16 + lp][0];
            uint2 lo = *(const uint2*)(rp + 4 * g);
            uint2 hi = *(const uint2*)(rp + 4 * g + 2);
            short8 afr = mk8(lo.x, lo.y, hi.x, hi.y);
            acc[tm][0] = __builtin_amdgcn_mfma_f32_16x16x32_bf16(afr, bfr[0], acc[tm][0], 0, 0, 0);
            acc[tm][1] = __builtin_amdgcn_mfma_f32_16x16x32_bf16(afr, bfr[1], acc[tm][1], 0, 0, 0);
        }
    }
    // epilogue: C layout row = 4g + reg, col = lane&15
#pragma unroll
    for (int tm = 0; tm < 4; tm++)
#pragma unroll
        for (int tn = 0; tn < 2; tn++) {
            int co = co0 + wn * 32 + tn * 16 + lp;
            float bv = bias[co];
#pragma unroll
            for (int r = 0; r < 4; r++) {
                int row = p0 + wm * 64 + tm * 16 + g * 4 + r;
                float val = acc[tm][tn][r] + bv;
                if (img)
                    F5[((size_t)(img - 1) * NPIX + row) * CCH + co] = val;
                else
                    Qbf[(size_t)row * CCH + co] = f2bfu(val * LOG2E);  // fold log2e for exp2
            }
        }
}

// ---------------- centroids (writes bf16 Cs + mask bias) ----------------
__global__ __launch_bounds__(256) void centroid_kernel(const float* __restrict__ F5, const float* __restrict__ dox,
                                                       uint16_t* __restrict__ Csbf, float* __restrict__ mbias) {
    int s = blockIdx.x, k = blockIdx.y;
    int p1 = s >> 4, p2 = s & 15;
    __shared__ float wfg[16];
    __shared__ int pix[16];
    int tid = threadIdx.x;
    if (tid < 16) {
        int hp = tid >> 2, wp = tid & 3;
        int y = p1 * 4 + hp, xx = p2 * 4 + wp;
        pix[tid] = y * 64 + xx;
        wfg[tid] = dox[(size_t)k * 65536 + (4 * y) * 256 + 4 * xx];
    }
    __syncthreads();
    float fsum = 0.0f;
#pragma unroll
    for (int l = 0; l < 16; l++) fsum += wfg[l];
    float bsum = 16.0f - fsum;
    int h = tid >> 5, dd = tid & 31;
    const float* Fk = F5 + (size_t)k * NPIX * CCH;
    float afg = 0.0f, abg = 0.0f;
#pragma unroll
    for (int l = 0; l < 16; l++) {
        float v = Fk[(size_t)pix[l] * CCH + h * 32 + dd];
        float wl = wfg[l];
        afg = fmaf(wl, v, afg);
        abg += v - wl * v;
    }
    float fgs = fmaxf(fsum, 1e-6f), bgs = fmaxf(bsum, 1e-6f);
    int mf = k * 512 + s, mbk = mf + 256;
    Csbf[((size_t)h * M2 + mf) * 32 + dd]  = f2bfu(afg / fgs);
    Csbf[((size_t)h * M2 + mbk) * 32 + dd] = f2bfu(abg / bgs);
    if (tid == 0) {
        mbias[mf]  = (fsum < 1.0f) ? -1e30f : 0.0f;
        mbias[mbk] = (bsum < 1.0f) ? -1e30f : 0.0f;
    }
}

// ---------------- attention (bf16 MFMA logits, sum-of-exp without max) ----------------
// grid (64 px-tiles, 8 heads, 2 slot-splits). 4 waves x 16px each, all 1280 slots of the split.
__global__ __launch_bounds__(256) void attn_mfma(
        const uint16_t* __restrict__ Qbf, const uint32_t* __restrict__ Cs32,
        const float* __restrict__ mbias, float* __restrict__ sf) {
    int head = blockIdx.y, split = blockIdx.z;
    int tid = threadIdx.x;
    int lane = tid & 63, wid = tid >> 6;
    int lp = lane & 15, g = lane >> 4;
    int p0w = blockIdx.x * 64 + wid * 16;
    __shared__ uint32_t Bl[64][18];
    __shared__ float mbl[64];

    // Q fragment: row = px (lane&15), k = 8g..8g+7 contiguous -> one 16B load
    const uint4* qp = (const uint4*)(Qbf + (size_t)(p0w + lp) * CCH + head * 32 + g * 8);
    uint4 qv = *qp;
    short8 aq = mk8(qv.x, qv.y, qv.z, qv.w);

    float s[4] = {0, 0, 0, 0}, f[4] = {0, 0, 0, 0};
    int slot = tid >> 2, q4 = tid & 3;
    int cbeg = split * 1280, cend = cbeg + 1280;
    for (int c0 = cbeg; c0 < cend; c0 += 64) {
        __syncthreads();
        uint4 v = *((const uint4*)(Cs32 + ((size_t)head * M2 + c0 + slot) * 16) + q4);
        Bl[slot][q4 * 4 + 0] = v.x; Bl[slot][q4 * 4 + 1] = v.y;
        Bl[slot][q4 * 4 + 2] = v.z; Bl[slot][q4 * 4 + 3] = v.w;
        if (tid < 64) mbl[tid] = mbias[c0 + tid];
        __syncthreads();
        bool fg = ((c0 & 511) < 256);   // uniform per 64-chunk
#pragma unroll
        for (int t = 0; t < 4; t++) {
            const uint32_t* rp = &Bl[t * 16 + lp][0];
            uint2 lo = *(const uint2*)(rp + 4 * g);
            uint2 hi = *(const uint2*)(rp + 4 * g + 2);
            short8 bf = mk8(lo.x, lo.y, hi.x, hi.y);
            f32x4 c = {0.f, 0.f, 0.f, 0.f};
            c = __builtin_amdgcn_mfma_f32_16x16x32_bf16(aq, bf, c, 0, 0, 0);
            float mbv = mbl[t * 16 + lp];
#pragma unroll
            for (int r = 0; r < 4; r++) {
                float e = __builtin_amdgcn_exp2f(c[r] + mbv);   // Q pre-scaled by log2e
                s[r] += e;
                if (fg) f[r] += e;
            }
        }
    }
    // reduce across the 16 lanes holding one row
#pragma unroll
    for (int r = 0; r < 4; r++) {
#pragma unroll
        for (int m = 1; m < 16; m <<= 1) {
            s[r] += __shfl_xor(s[r], m);
            f[r] += __shfl_xor(f[r], m);
        }
    }
    if (lp == 0) {
        float* so = sf + (size_t)head * NPIX;
        float* fo = sf + (size_t)(NH + head) * NPIX;
#pragma unroll
        for (int r = 0; r < 4; r++) {
            so[p0w + g * 4 + r] = s[r];
            fo[p0w + g * 4 + r] = f[r];
        }
    }
}

// ---------------- head mean over split partials ----------------
__global__ void mean_heads2(const float* __restrict__ sf, float* __restrict__ cm) {
    int idx = blockIdx.x * 256 + threadIdx.x;   // 16384
    int sc = idx >> 12, p = idx & 4095;
    const float* b = sf + (size_t)sc * 4 * NH * NPIX;
    float acc = 0.f;
#pragma unroll
    for (int h = 0; h < NH; h++) {
        float sv = b[(size_t)h * NPIX + p]        + b[(size_t)(16 + h) * NPIX + p];
        float fv = b[(size_t)(8 + h) * NPIX + p]  + b[(size_t)(24 + h) * NPIX + p];
        acc += fv / sv;
    }
    cm[idx] = 0.125f * acc;
}

// ---------------- convs ----------------
__global__ __launch_bounds__(256) void conv5x5(const float* __restrict__ in, const float* __restrict__ wgt,
                                               const float* __restrict__ bias, int Cin, float* __restrict__ out) {
    int oc = blockIdx.x;
    int p = blockIdx.y * 256 + threadIdx.x;
    int y = p >> 6, x = p & 63;
    float acc = bias[oc];
    for (int ic = 0; ic < Cin; ic++) {
        const float* ip = in + (size_t)ic * NPIX;
        const float* wp = wgt + ((size_t)oc * Cin + ic) * 25;
#pragma unroll
        for (int ky = 0; ky < 5; ky++) {
            int iy = y + ky - 2;
            if ((unsigned)iy >= 64u) continue;
#pragma unroll
            for (int kx = 0; kx < 5; kx++) {
                int ix = x + kx - 2;
                if ((unsigned)ix >= 64u) continue;
                acc = fmaf(ip[iy * 64 + ix], wp[ky * 5 + kx], acc);
            }
        }
    }
    out[(size_t)oc * NPIX + p] = acc;
}

__global__ __launch_bounds__(256) void conv3x3(const float* __restrict__ in, const float* __restrict__ wgt,
                                               const float* __restrict__ bias, int Cin, float* __restrict__ out) {
    int oc = blockIdx.x;
    int p = blockIdx.y * 256 + threadIdx.x;
    int y = p >> 6, x = p & 63;
    float acc = bias[oc];
    for (int ic = 0; ic < Cin; ic++) {
        const float* ip = in + (size_t)ic * NPIX;
        const float* wp = wgt + ((size_t)oc * Cin + ic) * 9;
#pragma unroll
        for (int ky = 0; ky < 3; ky++) {
            int iy = y + ky - 1;
            if ((unsigned)iy >= 64u) continue;
#pragma unroll
            for (int kx = 0; kx < 3; kx++) {
                int ix = x + kx - 1;
                if ((unsigned)ix >= 64u) continue;
                acc = fmaf(ip[iy * 64 + ix], wp[ky * 3 + kx], acc);
            }
        }
    }
    out[(size_t)oc * NPIX + p] = acc;
}

// ---------------- group norm ----------------
__global__ __launch_bounds__(256) void gn_stats(const float* __restrict__ in, int Cg, float* __restrict__ gnp) {
    int g = blockIdx.x;
    int n = Cg * NPIX;
    const float* base = in + (size_t)g * n;
    float s = 0.0f, s2 = 0.0f;
    for (int i = threadIdx.x; i < n; i += 256) {
        float v = base[i];
        s += v;
        s2 = fmaf(v, v, s2);
    }
#pragma unroll
    for (int off = 32; off; off >>= 1) {
        s += __shfl_down(s, off);
        s2 += __shfl_down(s2, off);
    }
    __shared__ float rs[4], rs2[4];
    int w = threadIdx.x >> 6;
    if ((threadIdx.x & 63) == 0) { rs[w] = s; rs2[w] = s2; }
    __syncthreads();
    if (threadIdx.x == 0) {
        float S = rs[0] + rs[1] + rs[2] + rs[3];
        float S2 = rs2[0] + rs2[1] + rs2[2] + rs2[3];
        float mu = S / n;
        float var = S2 / n - mu * mu;
        gnp[g * 2] = mu;
        gnp[g * 2 + 1] = rsqrtf(var + 1e-5f);
    }
}

__global__ void gn_apply_relu(const float* __restrict__ in, const float* __restrict__ gnp,
                              const float* __restrict__ gamma, const float* __restrict__ beta,
                              int Cg, float* __restrict__ out) {
    int idx = blockIdx.x * 256 + threadIdx.x;
    int c = idx >> 12;
    int g = c / Cg;
    float mu = gnp[g * 2], rs = gnp[g * 2 + 1];
    float v = (in[idx] - mu) * rs * gamma[c] + beta[c];
    out[idx] = v > 0.0f ? v : 0.0f;
}

// ---------------- launch ----------------
extern "C" void kernel_launch(void* const* d_in, const int* in_sizes, int n_in,
                              void* d_out, int out_size, void* d_ws, size_t ws_size,
                              hipStream_t stream) {
    const float* x[4] = {(const float*)d_in[0], (const float*)d_in[1], (const float*)d_in[2], (const float*)d_in[3]};
    const float* dox = (const float*)d_in[4];
    const float* wq  = (const float*)d_in[5];
    const float* bq  = (const float*)d_in[6];
    const float* wsm = (const float*)d_in[7];
    const float* bs  = (const float*)d_in[8];
    const float* cw1 = (const float*)d_in[9];
    const float* cb1 = (const float*)d_in[10];
    const float* g1  = (const float*)d_in[11];
    const float* be1 = (const float*)d_in[12];
    const float* cw2 = (const float*)d_in[13];
    const float* cb2 = (const float*)d_in[14];
    const float* g2  = (const float*)d_in[15];
    const float* be2 = (const float*)d_in[16];
    const float* cw3 = (const float*)d_in[17];
    const float* cb3 = (const float*)d_in[18];
    const float* g3  = (const float*)d_in[19];
    const float* be3 = (const float*)d_in[20];

    float* wsf = (float*)d_ws;
    float* F5 = wsf;                                        // 5*4096*256 = 5242880 f
    uint16_t* Qbf  = (uint16_t*)(F5 + 5242880);             // 1048576 us = 524288 f
    uint16_t* Csbf = (uint16_t*)(F5 + 5242880 + 524288);    // 655360 us = 327680 f
    float* mbias = F5 + 5242880 + 524288 + 327680;          // 2560
    float* sfbuf = mbias + 2560;                            // 4*2*2*8*4096 = 524288
    float* cm = sfbuf + 524288;                             // 16384
    float* h1 = cm + 16384;                                 // 65536
    float* h2 = h1 + 65536;                                 // 262144
    float* h3 = h2 + 262144;                                // 524288
    float* gnp = h3 + 524288;                               // 8

    for (int sc = 0; sc < 4; sc++) {
        feat_gemm_mfma<<<dim3(32, 4, 6), 256, 0, stream>>>(x[sc], wq, wsm, bq, bs, F5, Qbf);
        centroid_kernel<<<dim3(256, 5), 256, 0, stream>>>(F5, dox, Csbf, mbias);
        attn_mfma<<<dim3(64, NH, 2), 256, 0, stream>>>(Qbf, (const uint32_t*)Csbf, mbias,
                                                       sfbuf + (size_t)sc * 4 * NH * NPIX);
    }

    mean_heads2<<<64, 256, 0, stream>>>(sfbuf, cm);

    conv5x5<<<dim3(16, 16), 256, 0, stream>>>(cm, cw1, cb1, 4, h1);
    gn_stats<<<4, 256, 0, stream>>>(h1, 4, gnp);
    gn_apply_relu<<<(16 * NPIX) / 256, 256, 0, stream>>>(h1, gnp, g1, be1, 4, h1);

    conv5x5<<<dim3(64, 16), 256, 0, stream>>>(h1, cw2, cb2, 16, h2);
    gn_stats<<<4, 256, 0, stream>>>(h2, 16, gnp);
    gn_apply_relu<<<(64 * NPIX) / 256, 256, 0, stream>>>(h2, gnp, g2, be2, 16, h2);

    conv3x3<<<dim3(128, 16), 256, 0, stream>>>(h2, cw3, cb3, 64, h3);
    gn_stats<<<4, 256, 0, stream>>>(h3, 32, gnp);
    gn_apply_relu<<<(128 * NPIX) / 256, 256, 0, stream>>>(h3, gnp, g3, be3, 32, (float*)d_out);
}

// Round 3
// 378.086 us; speedup vs baseline: 2.8909x; 1.5202x over previous
//
#include <hip/hip_runtime.h>
#include <hip/hip_bf16.h>
#include <stdint.h>

#define CCH 256
#define NPIX 4096      // 64*64
#define NH 8
#define M2 2560        // K*2*S
#define LOG2E 1.44269504088896f
#define GN_NB 32

typedef __attribute__((ext_vector_type(8))) short short8;
typedef __attribute__((ext_vector_type(4))) float f32x4;

__device__ __forceinline__ uint16_t f2bfu(float f) {
    uint32_t u = __builtin_bit_cast(uint32_t, f);
    return (uint16_t)((u + 0x7FFFu + ((u >> 16) & 1u)) >> 16);   // RNE
}
__device__ __forceinline__ uint32_t pack_bf2(float a, float b) {
    return (uint32_t)f2bfu(a) | ((uint32_t)f2bfu(b) << 16);
}
__device__ __forceinline__ short8 mk8(uint32_t a, uint32_t b, uint32_t c, uint32_t d) {
    union { uint32_t u[4]; short8 s; } t;
    t.u[0] = a; t.u[1] = b; t.u[2] = c; t.u[3] = d;
    return t.s;
}

// ---------------- feature GEMM (bf16 MFMA): F[img][px][co] = X[img][:, px] . W[co][:] + b ----------------
// block: 128 px x 64 co, 4 waves (each 64px x 32co = 4x2 tiles of 16x16), K-step 32.
__global__ __launch_bounds__(256) void feat_gemm_mfma(
        const float* __restrict__ x, const float* __restrict__ wq, const float* __restrict__ wsm,
        const float* __restrict__ bq, const float* __restrict__ bs,
        float* __restrict__ F5, uint16_t* __restrict__ Qbf) {
    int img = blockIdx.z;
    int p0 = blockIdx.x * 128, co0 = blockIdx.y * 64;
    const float* w    = img ? wsm : wq;
    const float* bias = img ? bs  : bq;
    const float* xim  = x + (size_t)img * CCH * NPIX;
    __shared__ uint32_t Al[128][18];   // [px][k-pair], pad 18 u32 rows (72B)
    int tid = threadIdx.x;
    int lane = tid & 63, wid = tid >> 6;
    int lp = lane & 15, g = lane >> 4;
    int wm = wid & 1, wn = wid >> 1;

    f32x4 acc[4][2] = {};
    int spx = tid & 127, kp0 = tid >> 7;

#pragma unroll
    for (int ks = 0; ks < 8; ks++) {
        int k0 = ks * 32;
        __syncthreads();
        // stage A tile (transpose + f32->bf16 pack): 128px x 32k
#pragma unroll
        for (int it = 0; it < 8; it++) {
            int kp = kp0 + it * 2;
            float v0 = xim[(size_t)(k0 + 2 * kp) * NPIX + p0 + spx];
            float v1 = xim[(size_t)(k0 + 2 * kp + 1) * NPIX + p0 + spx];
            Al[spx][kp] = pack_bf2(v0, v1);
        }
        __syncthreads();
        // B fragments straight from global w (row-major [co][ci] == B-frag layout)
        short8 bfr[2];
#pragma unroll
        for (int tn = 0; tn < 2; tn++) {
            int co = co0 + wn * 32 + tn * 16 + lp;
            const float* wr = w + (size_t)co * 256 + k0 + g * 8;
            float4 f0 = *(const float4*)wr;
            float4 f1 = *(const float4*)(wr + 4);
            bfr[tn] = mk8(pack_bf2(f0.x, f0.y), pack_bf2(f0.z, f0.w),
                          pack_bf2(f1.x, f1.y), pack_bf2(f1.z, f1.w));
        }
#pragma unroll
        for (int tm = 0; tm < 4; tm++) {
            const uint32_t* rp = &Al[wm * 64 + tm * 16 + lp][0];
            uint2 lo = *(const uint2*)(rp + 4 * g);
            uint2 hi = *(const uint2*)(rp + 4 * g + 2);
            short8 afr = mk8(lo.x, lo.y, hi.x, hi.y);
            acc[tm][0] = __builtin_amdgcn_mfma_f32_16x16x32_bf16(afr, bfr[0], acc[tm][0], 0, 0, 0);
            acc[tm][1] = __builtin_amdgcn_mfma_f32_16x16x32_bf16(afr, bfr[1], acc[tm][1], 0, 0, 0);
        }
    }
    // epilogue: C layout row = 4g + reg, col = lane&15
#pragma unroll
    for (int tm = 0; tm < 4; tm++)
#pragma unroll
        for (int tn = 0; tn < 2; tn++) {
            int co = co0 + wn * 32 + tn * 16 + lp;
            float bv = bias[co];
#pragma unroll
            for (int r = 0; r < 4; r++) {
                int row = p0 + wm * 64 + tm * 16 + g * 4 + r;
                float val = acc[tm][tn][r] + bv;
                if (img)
                    F5[((size_t)(img - 1) * NPIX + row) * CCH + co] = val;
                else
                    Qbf[(size_t)row * CCH + co] = f2bfu(val * LOG2E);  // fold log2e for exp2
            }
        }
}

// ---------------- centroids (writes bf16 Cs + mask bias) ----------------
__global__ __launch_bounds__(256) void centroid_kernel(const float* __restrict__ F5, const float* __restrict__ dox,
                                                       uint16_t* __restrict__ Csbf, float* __restrict__ mbias) {
    int s = blockIdx.x, k = blockIdx.y;
    int p1 = s >> 4, p2 = s & 15;
    __shared__ float wfg[16];
    __shared__ int pix[16];
    int tid = threadIdx.x;
    if (tid < 16) {
        int hp = tid >> 2, wp = tid & 3;
        int y = p1 * 4 + hp, xx = p2 * 4 + wp;
        pix[tid] = y * 64 + xx;
        wfg[tid] = dox[(size_t)k * 65536 + (4 * y) * 256 + 4 * xx];
    }
    __syncthreads();
    float fsum = 0.0f;
#pragma unroll
    for (int l = 0; l < 16; l++) fsum += wfg[l];
    float bsum = 16.0f - fsum;
    int h = tid >> 5, dd = tid & 31;
    const float* Fk = F5 + (size_t)k * NPIX * CCH;
    float afg = 0.0f, abg = 0.0f;
#pragma unroll
    for (int l = 0; l < 16; l++) {
        float v = Fk[(size_t)pix[l] * CCH + h * 32 + dd];
        float wl = wfg[l];
        afg = fmaf(wl, v, afg);
        abg += v - wl * v;
    }
    float fgs = fmaxf(fsum, 1e-6f), bgs = fmaxf(bsum, 1e-6f);
    int mf = k * 512 + s, mbk = mf + 256;
    Csbf[((size_t)h * M2 + mf) * 32 + dd]  = f2bfu(afg / fgs);
    Csbf[((size_t)h * M2 + mbk) * 32 + dd] = f2bfu(abg / bgs);
    if (tid == 0) {
        mbias[mf]  = (fsum < 1.0f) ? -1e30f : 0.0f;
        mbias[mbk] = (bsum < 1.0f) ? -1e30f : 0.0f;
    }
}

// ---------------- attention (bf16 MFMA logits, sum-of-exp without max) ----------------
// grid (64 px-tiles, 8 heads, 2 slot-splits). 4 waves x 16px each, all 1280 slots of the split.
__global__ __launch_bounds__(256) void attn_mfma(
        const uint16_t* __restrict__ Qbf, const uint32_t* __restrict__ Cs32,
        const float* __restrict__ mbias, float* __restrict__ sf) {
    int head = blockIdx.y, split = blockIdx.z;
    int tid = threadIdx.x;
    int lane = tid & 63, wid = tid >> 6;
    int lp = lane & 15, g = lane >> 4;
    int p0w = blockIdx.x * 64 + wid * 16;
    __shared__ uint32_t Bl[64][18];
    __shared__ float mbl[64];

    // Q fragment: row = px (lane&15), k = 8g..8g+7 contiguous -> one 16B load
    const uint4* qp = (const uint4*)(Qbf + (size_t)(p0w + lp) * CCH + head * 32 + g * 8);
    uint4 qv = *qp;
    short8 aq = mk8(qv.x, qv.y, qv.z, qv.w);

    float s[4] = {0, 0, 0, 0}, f[4] = {0, 0, 0, 0};
    int slot = tid >> 2, q4 = tid & 3;
    int cbeg = split * 1280, cend = cbeg + 1280;
    for (int c0 = cbeg; c0 < cend; c0 += 64) {
        __syncthreads();
        uint4 v = *((const uint4*)(Cs32 + ((size_t)head * M2 + c0 + slot) * 16) + q4);
        Bl[slot][q4 * 4 + 0] = v.x; Bl[slot][q4 * 4 + 1] = v.y;
        Bl[slot][q4 * 4 + 2] = v.z; Bl[slot][q4 * 4 + 3] = v.w;
        if (tid < 64) mbl[tid] = mbias[c0 + tid];
        __syncthreads();
        bool fg = ((c0 & 511) < 256);   // uniform per 64-chunk
#pragma unroll
        for (int t = 0; t < 4; t++) {
            const uint32_t* rp = &Bl[t * 16 + lp][0];
            uint2 lo = *(const uint2*)(rp + 4 * g);
            uint2 hi = *(const uint2*)(rp + 4 * g + 2);
            short8 bf = mk8(lo.x, lo.y, hi.x, hi.y);
            f32x4 c = {0.f, 0.f, 0.f, 0.f};
            c = __builtin_amdgcn_mfma_f32_16x16x32_bf16(aq, bf, c, 0, 0, 0);
            float mbv = mbl[t * 16 + lp];
#pragma unroll
            for (int r = 0; r < 4; r++) {
                float e = __builtin_amdgcn_exp2f(c[r] + mbv);   // Q pre-scaled by log2e
                s[r] += e;
                if (fg) f[r] += e;
            }
        }
    }
    // reduce across the 16 lanes holding one row
#pragma unroll
    for (int r = 0; r < 4; r++) {
#pragma unroll
        for (int m = 1; m < 16; m <<= 1) {
            s[r] += __shfl_xor(s[r], m);
            f[r] += __shfl_xor(f[r], m);
        }
    }
    if (lp == 0) {
        float* so = sf + (size_t)head * NPIX;
        float* fo = sf + (size_t)(NH + head) * NPIX;
#pragma unroll
        for (int r = 0; r < 4; r++) {
            so[p0w + g * 4 + r] = s[r];
            fo[p0w + g * 4 + r] = f[r];
        }
    }
}

// ---------------- head mean over split partials ----------------
__global__ void mean_heads2(const float* __restrict__ sf, float* __restrict__ cm) {
    int idx = blockIdx.x * 256 + threadIdx.x;   // 16384
    int sc = idx >> 12, p = idx & 4095;
    const float* b = sf + (size_t)sc * 4 * NH * NPIX;
    float acc = 0.f;
#pragma unroll
    for (int h = 0; h < NH; h++) {
        float sv = b[(size_t)h * NPIX + p]        + b[(size_t)(16 + h) * NPIX + p];
        float fv = b[(size_t)(8 + h) * NPIX + p]  + b[(size_t)(24 + h) * NPIX + p];
        acc += fv / sv;
    }
    cm[idx] = 0.125f * acc;
}

// ---------------- convs ----------------
__global__ __launch_bounds__(256) void conv5x5(const float* __restrict__ in, const float* __restrict__ wgt,
                                               const float* __restrict__ bias, int Cin, float* __restrict__ out) {
    int oc = blockIdx.x;
    int p = blockIdx.y * 256 + threadIdx.x;
    int y = p >> 6, x = p & 63;
    float acc = bias[oc];
    for (int ic = 0; ic < Cin; ic++) {
        const float* ip = in + (size_t)ic * NPIX;
        const float* wp = wgt + ((size_t)oc * Cin + ic) * 25;
#pragma unroll
        for (int ky = 0; ky < 5; ky++) {
            int iy = y + ky - 2;
            if ((unsigned)iy >= 64u) continue;
#pragma unroll
            for (int kx = 0; kx < 5; kx++) {
                int ix = x + kx - 2;
                if ((unsigned)ix >= 64u) continue;
                acc = fmaf(ip[iy * 64 + ix], wp[ky * 5 + kx], acc);
            }
        }
    }
    out[(size_t)oc * NPIX + p] = acc;
}

__global__ __launch_bounds__(256) void conv3x3(const float* __restrict__ in, const float* __restrict__ wgt,
                                               const float* __restrict__ bias, int Cin, float* __restrict__ out) {
    int oc = blockIdx.x;
    int p = blockIdx.y * 256 + threadIdx.x;
    int y = p >> 6, x = p & 63;
    float acc = bias[oc];
    for (int ic = 0; ic < Cin; ic++) {
        const float* ip = in + (size_t)ic * NPIX;
        const float* wp = wgt + ((size_t)oc * Cin + ic) * 9;
#pragma unroll
        for (int ky = 0; ky < 3; ky++) {
            int iy = y + ky - 1;
            if ((unsigned)iy >= 64u) continue;
#pragma unroll
            for (int kx = 0; kx < 3; kx++) {
                int ix = x + kx - 1;
                if ((unsigned)ix >= 64u) continue;
                acc = fmaf(ip[iy * 64 + ix], wp[ky * 3 + kx], acc);
            }
        }
    }
    out[(size_t)oc * NPIX + p] = acc;
}

// ---------------- group norm: stage 1 partial sums (multi-block, float4, grid-stride) ----------------
__global__ __launch_bounds__(256) void gn_part(const float* __restrict__ in, int Cg,
                                               float* __restrict__ part) {
    int g = blockIdx.x, b = blockIdx.y;
    int n4 = Cg * 1024;                       // float4 count per group
    const float4* base = (const float4*)(in + (size_t)g * Cg * NPIX);
    float s = 0.0f, s2 = 0.0f;
    for (int i = b * 256 + threadIdx.x; i < n4; i += GN_NB * 256) {
        float4 v = base[i];
        s += v.x + v.y + v.z + v.w;
        s2 = fmaf(v.x, v.x, s2); s2 = fmaf(v.y, v.y, s2);
        s2 = fmaf(v.z, v.z, s2); s2 = fmaf(v.w, v.w, s2);
    }
#pragma unroll
    for (int off = 32; off; off >>= 1) {
        s += __shfl_down(s, off);
        s2 += __shfl_down(s2, off);
    }
    __shared__ float rs[4], rs2[4];
    int w = threadIdx.x >> 6;
    if ((threadIdx.x & 63) == 0) { rs[w] = s; rs2[w] = s2; }
    __syncthreads();
    if (threadIdx.x == 0) {
        part[(g * GN_NB + b) * 2]     = rs[0] + rs[1] + rs[2] + rs[3];
        part[(g * GN_NB + b) * 2 + 1] = rs2[0] + rs2[1] + rs2[2] + rs2[3];
    }
}

// ---------------- group norm: stage 2 reduce partials + apply + relu (float4) ----------------
__global__ __launch_bounds__(256) void gn_apply_relu(const float* __restrict__ in, const float* __restrict__ part,
                                                     const float* __restrict__ gamma, const float* __restrict__ beta,
                                                     int Cg, float* __restrict__ out) {
    int idx4 = blockIdx.x * 256 + threadIdx.x;   // over float4s
    int c = idx4 >> 10;                           // 1024 f4 per channel
    int g = c / Cg;
    float s = 0.0f, s2 = 0.0f;
#pragma unroll
    for (int b = 0; b < GN_NB; b++) {
        s  += part[(g * GN_NB + b) * 2];
        s2 += part[(g * GN_NB + b) * 2 + 1];
    }
    float n = (float)(Cg * NPIX);
    float mu = s / n;
    float rstd = rsqrtf(s2 / n - mu * mu + 1e-5f);
    float ga = gamma[c] * rstd;
    float be = beta[c] - mu * ga;
    float4 v = ((const float4*)in)[idx4];
    float4 o;
    o.x = fmaf(v.x, ga, be); o.x = o.x > 0.f ? o.x : 0.f;
    o.y = fmaf(v.y, ga, be); o.y = o.y > 0.f ? o.y : 0.f;
    o.z = fmaf(v.z, ga, be); o.z = o.z > 0.f ? o.z : 0.f;
    o.w = fmaf(v.w, ga, be); o.w = o.w > 0.f ? o.w : 0.f;
    ((float4*)out)[idx4] = o;
}

// ---------------- launch ----------------
extern "C" void kernel_launch(void* const* d_in, const int* in_sizes, int n_in,
                              void* d_out, int out_size, void* d_ws, size_t ws_size,
                              hipStream_t stream) {
    const float* x[4] = {(const float*)d_in[0], (const float*)d_in[1], (const float*)d_in[2], (const float*)d_in[3]};
    const float* dox = (const float*)d_in[4];
    const float* wq  = (const float*)d_in[5];
    const float* bq  = (const float*)d_in[6];
    const float* wsm = (const float*)d_in[7];
    const float* bs  = (const float*)d_in[8];
    const float* cw1 = (const float*)d_in[9];
    const float* cb1 = (const float*)d_in[10];
    const float* g1  = (const float*)d_in[11];
    const float* be1 = (const float*)d_in[12];
    const float* cw2 = (const float*)d_in[13];
    const float* cb2 = (const float*)d_in[14];
    const float* g2  = (const float*)d_in[15];
    const float* be2 = (const float*)d_in[16];
    const float* cw3 = (const float*)d_in[17];
    const float* cb3 = (const float*)d_in[18];
    const float* g3  = (const float*)d_in[19];
    const float* be3 = (const float*)d_in[20];

    float* wsf = (float*)d_ws;
    float* F5 = wsf;                                        // 5*4096*256 = 5242880 f
    uint16_t* Qbf  = (uint16_t*)(F5 + 5242880);             // 1048576 us = 524288 f
    uint16_t* Csbf = (uint16_t*)(F5 + 5242880 + 524288);    // 655360 us = 327680 f
    float* mbias = F5 + 5242880 + 524288 + 327680;          // 2560
    float* sfbuf = mbias + 2560;                            // 4*2*2*8*4096 = 524288
    float* cm = sfbuf + 524288;                             // 16384
    float* h1 = cm + 16384;                                 // 65536
    float* h2 = h1 + 65536;                                 // 262144
    float* h3 = h2 + 262144;                                // 524288
    float* gnpart = h3 + 524288;                            // 4*32*2 = 256

    for (int sc = 0; sc < 4; sc++) {
        feat_gemm_mfma<<<dim3(32, 4, 6), 256, 0, stream>>>(x[sc], wq, wsm, bq, bs, F5, Qbf);
        centroid_kernel<<<dim3(256, 5), 256, 0, stream>>>(F5, dox, Csbf, mbias);
        attn_mfma<<<dim3(64, NH, 2), 256, 0, stream>>>(Qbf, (const uint32_t*)Csbf, mbias,
                                                       sfbuf + (size_t)sc * 4 * NH * NPIX);
    }

    mean_heads2<<<64, 256, 0, stream>>>(sfbuf, cm);

    conv5x5<<<dim3(16, 16), 256, 0, stream>>>(cm, cw1, cb1, 4, h1);
    gn_part<<<dim3(4, GN_NB), 256, 0, stream>>>(h1, 4, gnpart);
    gn_apply_relu<<<(16 * 1024) / 256, 256, 0, stream>>>(h1, gnpart, g1, be1, 4, h1);

    conv5x5<<<dim3(64, 16), 256, 0, stream>>>(h1, cw2, cb2, 16, h2);
    gn_part<<<dim3(4, GN_NB), 256, 0, stream>>>(h2, 16, gnpart);
    gn_apply_relu<<<(64 * 1024) / 256, 256, 0, stream>>>(h2, gnpart, g2, be2, 16, h2);

    conv3x3<<<dim3(128, 16), 256, 0, stream>>>(h2, cw3, cb3, 64, h3);
    gn_part<<<dim3(4, GN_NB), 256, 0, stream>>>(h3, 32, gnpart);
    gn_apply_relu<<<(128 * 1024) / 256, 256, 0, stream>>>(h3, gnpart, g3, be3, 32, (float*)d_out);
}

// Round 4
// 258.578 us; speedup vs baseline: 4.2271x; 1.4622x over previous
//
#include <hip/hip_runtime.h>
#include <hip/hip_bf16.h>
#include <stdint.h>

#define CCH 256
#define NPIX 4096      // 64*64
#define NH 8
#define M2 2560        // K*2*S
#define LOG2E 1.44269504088896f
#define GN_NB 32

typedef __attribute__((ext_vector_type(8))) short short8;
typedef __attribute__((ext_vector_type(4))) float f32x4;

__device__ __forceinline__ uint16_t f2bfu(float f) {
    uint32_t u = __builtin_bit_cast(uint32_t, f);
    return (uint16_t)((u + 0x7FFFu + ((u >> 16) & 1u)) >> 16);   // RNE
}
__device__ __forceinline__ uint32_t pack_bf2(float a, float b) {
    return (uint32_t)f2bfu(a) | ((uint32_t)f2bfu(b) << 16);
}
__device__ __forceinline__ short8 mk8(uint32_t a, uint32_t b, uint32_t c, uint32_t d) {
    union { uint32_t u[4]; short8 s; } t;
    t.u[0] = a; t.u[1] = b; t.u[2] = c; t.u[3] = d;
    return t.s;
}

// ---------------- feature GEMM (bf16 MFMA) ----------------
__global__ __launch_bounds__(256) void feat_gemm_mfma(
        const float* __restrict__ x, const float* __restrict__ wq, const float* __restrict__ wsm,
        const float* __restrict__ bq, const float* __restrict__ bs,
        float* __restrict__ F5, uint16_t* __restrict__ Qbf) {
    int img = blockIdx.z;
    int p0 = blockIdx.x * 128, co0 = blockIdx.y * 64;
    const float* w    = img ? wsm : wq;
    const float* bias = img ? bs  : bq;
    const float* xim  = x + (size_t)img * CCH * NPIX;
    __shared__ uint32_t Al[128][18];   // [px][k-pair], pad 18 u32 rows (72B)
    int tid = threadIdx.x;
    int lane = tid & 63, wid = tid >> 6;
    int lp = lane & 15, g = lane >> 4;
    int wm = wid & 1, wn = wid >> 1;

    f32x4 acc[4][2] = {};
    int spx = tid & 127, kp0 = tid >> 7;

#pragma unroll
    for (int ks = 0; ks < 8; ks++) {
        int k0 = ks * 32;
        __syncthreads();
#pragma unroll
        for (int it = 0; it < 8; it++) {
            int kp = kp0 + it * 2;
            float v0 = xim[(size_t)(k0 + 2 * kp) * NPIX + p0 + spx];
            float v1 = xim[(size_t)(k0 + 2 * kp + 1) * NPIX + p0 + spx];
            Al[spx][kp] = pack_bf2(v0, v1);
        }
        __syncthreads();
        short8 bfr[2];
#pragma unroll
        for (int tn = 0; tn < 2; tn++) {
            int co = co0 + wn * 32 + tn * 16 + lp;
            const float* wr = w + (size_t)co * 256 + k0 + g * 8;
            float4 f0 = *(const float4*)wr;
            float4 f1 = *(const float4*)(wr + 4);
            bfr[tn] = mk8(pack_bf2(f0.x, f0.y), pack_bf2(f0.z, f0.w),
                          pack_bf2(f1.x, f1.y), pack_bf2(f1.z, f1.w));
        }
#pragma unroll
        for (int tm = 0; tm < 4; tm++) {
            const uint32_t* rp = &Al[wm * 64 + tm * 16 + lp][0];
            uint2 lo = *(const uint2*)(rp + 4 * g);
            uint2 hi = *(const uint2*)(rp + 4 * g + 2);
            short8 afr = mk8(lo.x, lo.y, hi.x, hi.y);
            acc[tm][0] = __builtin_amdgcn_mfma_f32_16x16x32_bf16(afr, bfr[0], acc[tm][0], 0, 0, 0);
            acc[tm][1] = __builtin_amdgcn_mfma_f32_16x16x32_bf16(afr, bfr[1], acc[tm][1], 0, 0, 0);
        }
    }
#pragma unroll
    for (int tm = 0; tm < 4; tm++)
#pragma unroll
        for (int tn = 0; tn < 2; tn++) {
            int co = co0 + wn * 32 + tn * 16 + lp;
            float bv = bias[co];
#pragma unroll
            for (int r = 0; r < 4; r++) {
                int row = p0 + wm * 64 + tm * 16 + g * 4 + r;
                float val = acc[tm][tn][r] + bv;
                if (img)
                    F5[((size_t)(img - 1) * NPIX + row) * CCH + co] = val;
                else
                    Qbf[(size_t)row * CCH + co] = f2bfu(val * LOG2E);
            }
        }
}

// ---------------- centroids ----------------
__global__ __launch_bounds__(256) void centroid_kernel(const float* __restrict__ F5, const float* __restrict__ dox,
                                                       uint16_t* __restrict__ Csbf, float* __restrict__ mbias) {
    int s = blockIdx.x, k = blockIdx.y;
    int p1 = s >> 4, p2 = s & 15;
    __shared__ float wfg[16];
    __shared__ int pix[16];
    int tid = threadIdx.x;
    if (tid < 16) {
        int hp = tid >> 2, wp = tid & 3;
        int y = p1 * 4 + hp, xx = p2 * 4 + wp;
        pix[tid] = y * 64 + xx;
        wfg[tid] = dox[(size_t)k * 65536 + (4 * y) * 256 + 4 * xx];
    }
    __syncthreads();
    float fsum = 0.0f;
#pragma unroll
    for (int l = 0; l < 16; l++) fsum += wfg[l];
    float bsum = 16.0f - fsum;
    int h = tid >> 5, dd = tid & 31;
    const float* Fk = F5 + (size_t)k * NPIX * CCH;
    float afg = 0.0f, abg = 0.0f;
#pragma unroll
    for (int l = 0; l < 16; l++) {
        float v = Fk[(size_t)pix[l] * CCH + h * 32 + dd];
        float wl = wfg[l];
        afg = fmaf(wl, v, afg);
        abg += v - wl * v;
    }
    float fgs = fmaxf(fsum, 1e-6f), bgs = fmaxf(bsum, 1e-6f);
    int mf = k * 512 + s, mbk = mf + 256;
    Csbf[((size_t)h * M2 + mf) * 32 + dd]  = f2bfu(afg / fgs);
    Csbf[((size_t)h * M2 + mbk) * 32 + dd] = f2bfu(abg / bgs);
    if (tid == 0) {
        mbias[mf]  = (fsum < 1.0f) ? -1e30f : 0.0f;
        mbias[mbk] = (bsum < 1.0f) ? -1e30f : 0.0f;
    }
}

// ---------------- attention ----------------
__global__ __launch_bounds__(256) void attn_mfma(
        const uint16_t* __restrict__ Qbf, const uint32_t* __restrict__ Cs32,
        const float* __restrict__ mbias, float* __restrict__ sf) {
    int head = blockIdx.y, split = blockIdx.z;
    int tid = threadIdx.x;
    int lane = tid & 63, wid = tid >> 6;
    int lp = lane & 15, g = lane >> 4;
    int p0w = blockIdx.x * 64 + wid * 16;
    __shared__ uint32_t Bl[64][18];
    __shared__ float mbl[64];

    const uint4* qp = (const uint4*)(Qbf + (size_t)(p0w + lp) * CCH + head * 32 + g * 8);
    uint4 qv = *qp;
    short8 aq = mk8(qv.x, qv.y, qv.z, qv.w);

    float s[4] = {0, 0, 0, 0}, f[4] = {0, 0, 0, 0};
    int slot = tid >> 2, q4 = tid & 3;
    int cbeg = split * 1280, cend = cbeg + 1280;
    for (int c0 = cbeg; c0 < cend; c0 += 64) {
        __syncthreads();
        uint4 v = *((const uint4*)(Cs32 + ((size_t)head * M2 + c0 + slot) * 16) + q4);
        Bl[slot][q4 * 4 + 0] = v.x; Bl[slot][q4 * 4 + 1] = v.y;
        Bl[slot][q4 * 4 + 2] = v.z; Bl[slot][q4 * 4 + 3] = v.w;
        if (tid < 64) mbl[tid] = mbias[c0 + tid];
        __syncthreads();
        bool fg = ((c0 & 511) < 256);
#pragma unroll
        for (int t = 0; t < 4; t++) {
            const uint32_t* rp = &Bl[t * 16 + lp][0];
            uint2 lo = *(const uint2*)(rp + 4 * g);
            uint2 hi = *(const uint2*)(rp + 4 * g + 2);
            short8 bf = mk8(lo.x, lo.y, hi.x, hi.y);
            f32x4 c = {0.f, 0.f, 0.f, 0.f};
            c = __builtin_amdgcn_mfma_f32_16x16x32_bf16(aq, bf, c, 0, 0, 0);
            float mbv = mbl[t * 16 + lp];
#pragma unroll
            for (int r = 0; r < 4; r++) {
                float e = __builtin_amdgcn_exp2f(c[r] + mbv);
                s[r] += e;
                if (fg) f[r] += e;
            }
        }
    }
#pragma unroll
    for (int r = 0; r < 4; r++) {
#pragma unroll
        for (int m = 1; m < 16; m <<= 1) {
            s[r] += __shfl_xor(s[r], m);
            f[r] += __shfl_xor(f[r], m);
        }
    }
    if (lp == 0) {
        float* so = sf + (size_t)head * NPIX;
        float* fo = sf + (size_t)(NH + head) * NPIX;
#pragma unroll
        for (int r = 0; r < 4; r++) {
            so[p0w + g * 4 + r] = s[r];
            fo[p0w + g * 4 + r] = f[r];
        }
    }
}

// ---------------- head mean over split partials ----------------
__global__ void mean_heads2(const float* __restrict__ sf, float* __restrict__ cm) {
    int idx = blockIdx.x * 256 + threadIdx.x;   // 16384
    int sc = idx >> 12, p = idx & 4095;
    const float* b = sf + (size_t)sc * 4 * NH * NPIX;
    float acc = 0.f;
#pragma unroll
    for (int h = 0; h < NH; h++) {
        float sv = b[(size_t)h * NPIX + p]        + b[(size_t)(16 + h) * NPIX + p];
        float fv = b[(size_t)(8 + h) * NPIX + p]  + b[(size_t)(24 + h) * NPIX + p];
        acc += fv / sv;
    }
    cm[idx] = 0.125f * acc;
}

// ---------------- weight prepack: Wk[ck][oc][32] bf16, zero-filled past K ----------------
__global__ void prep_w(const float* __restrict__ w, uint16_t* __restrict__ Wk,
                       int Cin, int Cout, int K2, int CK) {
    int idx = blockIdx.x * 256 + threadIdx.x;
    int total = CK * Cout * 32;
    if (idx >= total) return;
    int kk = idx & 31;
    int oc = (idx >> 5) % Cout;
    int ck = idx / (32 * Cout);
    int k = ck * 32 + kk;
    int tap = k / Cin, ic = k % Cin;
    float v = (tap < K2) ? w[((size_t)oc * Cin + ic) * K2 + tap] : 0.0f;
    Wk[idx] = f2bfu(v);
}

// ---------------- implicit-GEMM conv via MFMA ----------------
// Block: output row y (64 px = 4 M-tiles) x min(Cout,64) oc. 4 waves.
// LDS: CIN>=8: Xs[r][ic/8][px+2pad][8ic] (16B units); CIN==4: Xs[r][px+2pad][4ic] (8B units).
template<int CIN, int COUT, int KSZ>
__global__ __launch_bounds__(256) void conv_mfma(
        const float* __restrict__ in, const uint16_t* __restrict__ Wk,
        const float* __restrict__ bias, float* __restrict__ out) {
    constexpr int PAD = KSZ / 2;
    constexpr int NTAP = KSZ * KSZ;
    constexpr int K = CIN * NTAP;
    constexpr int CK = (K + 31) / 32;
    constexpr int PXP = 64 + 2 * PAD;
    constexpr int ICB = (CIN >= 8) ? CIN / 8 : 1;
    __shared__ uint16_t Xs[KSZ * PXP * CIN];
    int tid = threadIdx.x;
    int lane = tid & 63, wv = tid >> 6;
    int lp = lane & 15, g = lane >> 4;
    int y = blockIdx.x;
    int oc0 = blockIdx.y * 64;

    if (CIN >= 8) {
        for (int idx = tid; idx < KSZ * ICB * PXP; idx += 256) {
            int pxp = idx % PXP; int rem = idx / PXP;
            int icb = rem % ICB; int r = rem / ICB;
            int gy = y + r - PAD, gx = pxp - PAD;
            bool ok = ((unsigned)gy < 64u) && ((unsigned)gx < 64u);
            const float* ip = in + (size_t)(icb * 8) * NPIX + gy * 64 + gx;
            uint32_t wb[4];
#pragma unroll
            for (int j = 0; j < 4; j++) {
                float v0 = ok ? ip[(size_t)(2 * j) * NPIX] : 0.f;
                float v1 = ok ? ip[(size_t)(2 * j + 1) * NPIX] : 0.f;
                wb[j] = pack_bf2(v0, v1);
            }
            *(uint4*)&Xs[(size_t)idx * 8] = make_uint4(wb[0], wb[1], wb[2], wb[3]);
        }
    } else {
        for (int idx = tid; idx < KSZ * PXP; idx += 256) {
            int pxp = idx % PXP; int r = idx / PXP;
            int gy = y + r - PAD, gx = pxp - PAD;
            bool ok = ((unsigned)gy < 64u) && ((unsigned)gx < 64u);
            const float* ip = in + (size_t)gy * 64 + gx;
            float v0 = ok ? ip[0] : 0.f, v1 = ok ? ip[NPIX] : 0.f;
            float v2 = ok ? ip[2 * NPIX] : 0.f, v3 = ok ? ip[3 * NPIX] : 0.f;
            *(uint2*)&Xs[(size_t)idx * 4] = make_uint2(pack_bf2(v0, v1), pack_bf2(v2, v3));
        }
    }
    __syncthreads();

    int tmb, tme, tn;
    if (COUT >= 64) { tn = wv; tmb = 0; tme = 4; }
    else            { tn = 0;  tmb = wv; tme = wv + 1; }
    int oc = oc0 + tn * 16 + lp;
    f32x4 acc[4] = {};

#pragma unroll
    for (int ck = 0; ck < CK; ck++) {
        const uint16_t* wp = Wk + ((size_t)ck * COUT + oc) * 32 + g * 8;
        uint4 bw = *(const uint4*)wp;
        short8 bfr = mk8(bw.x, bw.y, bw.z, bw.w);
        if (CIN >= 8) {
            int gk = ck * 4 + g;
            int tap = gk / ICB; if (tap > NTAP - 1) tap = NTAP - 1;   // zero-filled B past K
            int icb = gk % ICB;
            int r = tap / KSZ, dx = tap % KSZ;
            int base = (r * ICB + icb) * PXP * 8;
            for (int tm = tmb; tm < tme; tm++) {
                int pxp = tm * 16 + lp + dx;
                uint4 av = *(const uint4*)&Xs[base + pxp * 8];
                short8 afr = mk8(av.x, av.y, av.z, av.w);
                acc[tm] = __builtin_amdgcn_mfma_f32_16x16x32_bf16(afr, bfr, acc[tm], 0, 0, 0);
            }
        } else {
            int gk = ck * 4 + g;
            int t0 = 2 * gk;     if (t0 > NTAP - 1) t0 = NTAP - 1;
            int t1 = 2 * gk + 1; if (t1 > NTAP - 1) t1 = NTAP - 1;
            int r0 = t0 / KSZ, dx0 = t0 % KSZ;
            int r1 = t1 / KSZ, dx1 = t1 % KSZ;
            for (int tm = tmb; tm < tme; tm++) {
                uint2 a0 = *(const uint2*)&Xs[((size_t)(r0 * PXP + tm * 16 + lp + dx0)) * 4];
                uint2 a1 = *(const uint2*)&Xs[((size_t)(r1 * PXP + tm * 16 + lp + dx1)) * 4];
                short8 afr = mk8(a0.x, a0.y, a1.x, a1.y);
                acc[tm] = __builtin_amdgcn_mfma_f32_16x16x32_bf16(afr, bfr, acc[tm], 0, 0, 0);
            }
        }
    }
    float bv = bias[oc];
    for (int tm = tmb; tm < tme; tm++)
#pragma unroll
        for (int r = 0; r < 4; r++) {
            int px = tm * 16 + g * 4 + r;
            out[(size_t)oc * NPIX + y * 64 + px] = acc[tm][r] + bv;
        }
}

// ---------------- group norm: stage 1 partial sums ----------------
__global__ __launch_bounds__(256) void gn_part(const float* __restrict__ in, int Cg,
                                               float* __restrict__ part) {
    int g = blockIdx.x, b = blockIdx.y;
    int n4 = Cg * 1024;
    const float4* base = (const float4*)(in + (size_t)g * Cg * NPIX);
    float s = 0.0f, s2 = 0.0f;
    for (int i = b * 256 + threadIdx.x; i < n4; i += GN_NB * 256) {
        float4 v = base[i];
        s += v.x + v.y + v.z + v.w;
        s2 = fmaf(v.x, v.x, s2); s2 = fmaf(v.y, v.y, s2);
        s2 = fmaf(v.z, v.z, s2); s2 = fmaf(v.w, v.w, s2);
    }
#pragma unroll
    for (int off = 32; off; off >>= 1) {
        s += __shfl_down(s, off);
        s2 += __shfl_down(s2, off);
    }
    __shared__ float rs[4], rs2[4];
    int w = threadIdx.x >> 6;
    if ((threadIdx.x & 63) == 0) { rs[w] = s; rs2[w] = s2; }
    __syncthreads();
    if (threadIdx.x == 0) {
        part[(g * GN_NB + b) * 2]     = rs[0] + rs[1] + rs[2] + rs[3];
        part[(g * GN_NB + b) * 2 + 1] = rs2[0] + rs2[1] + rs2[2] + rs2[3];
    }
}

// ---------------- group norm: stage 2 apply + relu ----------------
__global__ __launch_bounds__(256) void gn_apply_relu(const float* __restrict__ in, const float* __restrict__ part,
                                                     const float* __restrict__ gamma, const float* __restrict__ beta,
                                                     int Cg, float* __restrict__ out) {
    int idx4 = blockIdx.x * 256 + threadIdx.x;
    int c = idx4 >> 10;
    int g = c / Cg;
    float s = 0.0f, s2 = 0.0f;
#pragma unroll
    for (int b = 0; b < GN_NB; b++) {
        s  += part[(g * GN_NB + b) * 2];
        s2 += part[(g * GN_NB + b) * 2 + 1];
    }
    float n = (float)(Cg * NPIX);
    float mu = s / n;
    float rstd = rsqrtf(s2 / n - mu * mu + 1e-5f);
    float ga = gamma[c] * rstd;
    float be = beta[c] - mu * ga;
    float4 v = ((const float4*)in)[idx4];
    float4 o;
    o.x = fmaf(v.x, ga, be); o.x = o.x > 0.f ? o.x : 0.f;
    o.y = fmaf(v.y, ga, be); o.y = o.y > 0.f ? o.y : 0.f;
    o.z = fmaf(v.z, ga, be); o.z = o.z > 0.f ? o.z : 0.f;
    o.w = fmaf(v.w, ga, be); o.w = o.w > 0.f ? o.w : 0.f;
    ((float4*)out)[idx4] = o;
}

// ---------------- launch ----------------
extern "C" void kernel_launch(void* const* d_in, const int* in_sizes, int n_in,
                              void* d_out, int out_size, void* d_ws, size_t ws_size,
                              hipStream_t stream) {
    const float* x[4] = {(const float*)d_in[0], (const float*)d_in[1], (const float*)d_in[2], (const float*)d_in[3]};
    const float* dox = (const float*)d_in[4];
    const float* wq  = (const float*)d_in[5];
    const float* bq  = (const float*)d_in[6];
    const float* wsm = (const float*)d_in[7];
    const float* bs  = (const float*)d_in[8];
    const float* cw1 = (const float*)d_in[9];
    const float* cb1 = (const float*)d_in[10];
    const float* g1  = (const float*)d_in[11];
    const float* be1 = (const float*)d_in[12];
    const float* cw2 = (const float*)d_in[13];
    const float* cb2 = (const float*)d_in[14];
    const float* g2  = (const float*)d_in[15];
    const float* be2 = (const float*)d_in[16];
    const float* cw3 = (const float*)d_in[17];
    const float* cb3 = (const float*)d_in[18];
    const float* g3  = (const float*)d_in[19];
    const float* be3 = (const float*)d_in[20];

    float* wsf = (float*)d_ws;
    float* F5 = wsf;                                        // 5*4096*256 = 5242880 f
    uint16_t* Qbf  = (uint16_t*)(F5 + 5242880);             // 524288 f
    uint16_t* Csbf = (uint16_t*)(F5 + 5242880 + 524288);    // 327680 f
    float* mbias = F5 + 5242880 + 524288 + 327680;          // 2560
    float* sfbuf = mbias + 2560;                            // 524288
    float* cm = sfbuf + 524288;                             // 16384
    float* h1 = cm + 16384;                                 // 65536
    float* h2 = h1 + 65536;                                 // 262144
    float* h3 = h2 + 262144;                                // 524288
    float* gnpart = h3 + 524288;                            // 256
    uint16_t* Wk1 = (uint16_t*)(gnpart + 256);              // 4*16*32 = 2048 u16
    uint16_t* Wk2 = Wk1 + 4 * 16 * 32;                      // 13*64*32 = 26624 u16
    uint16_t* Wk3 = Wk2 + 13 * 64 * 32;                     // 18*128*32 = 73728 u16

    // weight prepack (independent of everything else)
    prep_w<<<(4 * 16 * 32 + 255) / 256, 256, 0, stream>>>(cw1, Wk1, 4, 16, 25, 4);
    prep_w<<<(13 * 64 * 32 + 255) / 256, 256, 0, stream>>>(cw2, Wk2, 16, 64, 25, 13);
    prep_w<<<(18 * 128 * 32 + 255) / 256, 256, 0, stream>>>(cw3, Wk3, 64, 128, 9, 18);

    for (int sc = 0; sc < 4; sc++) {
        feat_gemm_mfma<<<dim3(32, 4, 6), 256, 0, stream>>>(x[sc], wq, wsm, bq, bs, F5, Qbf);
        centroid_kernel<<<dim3(256, 5), 256, 0, stream>>>(F5, dox, Csbf, mbias);
        attn_mfma<<<dim3(64, NH, 2), 256, 0, stream>>>(Qbf, (const uint32_t*)Csbf, mbias,
                                                       sfbuf + (size_t)sc * 4 * NH * NPIX);
    }

    mean_heads2<<<64, 256, 0, stream>>>(sfbuf, cm);

    conv_mfma<4, 16, 5><<<dim3(64, 1), 256, 0, stream>>>(cm, Wk1, cb1, h1);
    gn_part<<<dim3(4, GN_NB), 256, 0, stream>>>(h1, 4, gnpart);
    gn_apply_relu<<<(16 * 1024) / 256, 256, 0, stream>>>(h1, gnpart, g1, be1, 4, h1);

    conv_mfma<16, 64, 5><<<dim3(64, 1), 256, 0, stream>>>(h1, Wk2, cb2, h2);
    gn_part<<<dim3(4, GN_NB), 256, 0, stream>>>(h2, 16, gnpart);
    gn_apply_relu<<<(64 * 1024) / 256, 256, 0, stream>>>(h2, gnpart, g2, be2, 16, h2);

    conv_mfma<64, 128, 3><<<dim3(64, 2), 256, 0, stream>>>(h2, Wk3, cb3, h3);
    gn_part<<<dim3(4, GN_NB), 256, 0, stream>>>(h3, 32, gnpart);
    gn_apply_relu<<<(128 * 1024) / 256, 256, 0, stream>>>(h3, gnpart, g3, be3, 32, (float*)d_out);
}